// Round 1
// baseline (689.638 us; speedup 1.0000x reference)
//
#include <hip/hip_runtime.h>
#include <hip/hip_bf16.h>
#include <cstdint>

// ---- problem dims ----
#define L_SEQ   2048
#define DM      1024   // d_model
#define DI      2048   // d_inner
#define DXB     512
#define DS      16     // d_state
#define DTR     64     // dt_rank
#define GH      128    // C-heads = DI/DS
#define DP      5184   // 2*DI + 2*DXB + DTR

// zxbcdt column offsets
#define OFF_Z   0
#define OFF_X   2048
#define OFF_B   2560
#define OFF_C   3072
#define OFF_DT  5120

// scan segmentation
#define NSEG    8
#define SEGLEN  256
#define CHUNK   64

__device__ __forceinline__ float siluf(float x) {
  return x / (1.f + __expf(-x));
}
__device__ __forceinline__ float softplusf(float x) {
  return x > 20.f ? x : log1pf(__expf(x));
}

// ---------------------------------------------------------------------------
// Generic fp32 GEMM: C[M,N] (+)= A[M, lda; col offset aoff][k] * B[k, ldb]
// Block tile 128x128, BK=16, 256 threads, 8x8 micro-tile (split 4+4 rows/cols).
// MODE 0: plain store. MODE 1: softplus(acc + 2*bias[col]). MODE 2: atomicAdd
// (split-K over blockIdx.z windows of Klen).
// Requires: M % 128 == 0, N % 4 == 0, Klen % 16 == 0.
// ---------------------------------------------------------------------------
template<int MODE>
__global__ __launch_bounds__(256, 2) void gemm128(
    const float* __restrict__ A, int lda, int aoff,
    const float* __restrict__ B, int ldb,
    float* __restrict__ C, int ldc,
    const float* __restrict__ bias,
    int M, int N, int Kbeg, int Klen)
{
  __shared__ __align__(16) float As[16][132];  // [k][m] (transposed), +4 pad
  __shared__ __align__(16) float Bs[16][132];  // [k][n]

  const int tid = threadIdx.x;
  const int row0 = blockIdx.y * 128;
  const int col0 = blockIdx.x * 128;
  const int kb = Kbeg + blockIdx.z * Klen;

  const int tx = tid & 15, ty = tid >> 4;
  const int ar = tid >> 2, aq = (tid & 3) << 2;   // A stage: rows ar, ar+64; k-col aq..aq+3
  const int br = tid >> 5, bq = (tid & 31) << 2;  // B stage: k-rows br, br+8; col bq..bq+3

  float acc[8][8];
#pragma unroll
  for (int i = 0; i < 8; ++i)
#pragma unroll
    for (int j = 0; j < 8; ++j) acc[i][j] = 0.f;

  float4 ra0, ra1, rb0, rb1;
  const int ktiles = Klen >> 4;

  auto loadG = [&](int kt) {
    const int k0 = kb + (kt << 4);
    const float* Ap = A + (size_t)(row0 + ar) * lda + aoff + k0 + aq;
    ra0 = *(const float4*)Ap;
    ra1 = *(const float4*)(Ap + (size_t)64 * lda);
    const int cb_ = col0 + bq;
    if (cb_ < N) {
      const float* Bp = B + (size_t)(k0 + br) * ldb + cb_;
      rb0 = *(const float4*)Bp;
      rb1 = *(const float4*)(Bp + (size_t)8 * ldb);
    } else {
      rb0 = make_float4(0.f, 0.f, 0.f, 0.f);
      rb1 = make_float4(0.f, 0.f, 0.f, 0.f);
    }
  };

  loadG(0);
  for (int kt = 0; kt < ktiles; ++kt) {
    __syncthreads();
    // regs -> LDS (A transposed so frag reads are contiguous float4)
    As[aq + 0][ar] = ra0.x; As[aq + 1][ar] = ra0.y;
    As[aq + 2][ar] = ra0.z; As[aq + 3][ar] = ra0.w;
    As[aq + 0][ar + 64] = ra1.x; As[aq + 1][ar + 64] = ra1.y;
    As[aq + 2][ar + 64] = ra1.z; As[aq + 3][ar + 64] = ra1.w;
    *(float4*)&Bs[br][bq] = rb0;
    *(float4*)&Bs[br + 8][bq] = rb1;
    __syncthreads();
    if (kt + 1 < ktiles) loadG(kt + 1);  // prefetch next tile during compute

#pragma unroll
    for (int k = 0; k < 16; ++k) {
      float4 a0 = *(const float4*)&As[k][ty * 4];
      float4 a1 = *(const float4*)&As[k][ty * 4 + 64];
      float4 b0 = *(const float4*)&Bs[k][tx * 4];
      float4 b1 = *(const float4*)&Bs[k][tx * 4 + 64];
      float av[8] = {a0.x, a0.y, a0.z, a0.w, a1.x, a1.y, a1.z, a1.w};
      float bv[8] = {b0.x, b0.y, b0.z, b0.w, b1.x, b1.y, b1.z, b1.w};
#pragma unroll
      for (int i = 0; i < 8; ++i)
#pragma unroll
        for (int j = 0; j < 8; ++j)
          acc[i][j] = fmaf(av[i], bv[j], acc[i][j]);
    }
  }

  // epilogue: rows {ty*4+i, 64+ty*4+i}, cols {tx*4+j, 64+tx*4+j}
#pragma unroll
  for (int half = 0; half < 2; ++half) {
#pragma unroll
    for (int i = 0; i < 4; ++i) {
      const int rr = row0 + half * 64 + ty * 4 + i;
      if (rr >= M) continue;
      const int ii = half * 4 + i;
#pragma unroll
      for (int jh = 0; jh < 2; ++jh) {
        const int cc = col0 + jh * 64 + tx * 4;
        if (cc >= N) continue;
        const int jj = jh * 4;
        float* Cp = C + (size_t)rr * ldc + cc;
        if (MODE == 0) {
          float4 v = make_float4(acc[ii][jj], acc[ii][jj + 1], acc[ii][jj + 2], acc[ii][jj + 3]);
          *(float4*)Cp = v;
        } else if (MODE == 1) {
          float4 bi = *(const float4*)&bias[cc];
          float4 v;
          v.x = softplusf(acc[ii][jj + 0] + 2.f * bi.x);
          v.y = softplusf(acc[ii][jj + 1] + 2.f * bi.y);
          v.z = softplusf(acc[ii][jj + 2] + 2.f * bi.z);
          v.w = softplusf(acc[ii][jj + 3] + 2.f * bi.w);
          *(float4*)Cp = v;
        } else {
          atomicAdd(Cp + 0, acc[ii][jj + 0]);
          atomicAdd(Cp + 1, acc[ii][jj + 1]);
          atomicAdd(Cp + 2, acc[ii][jj + 2]);
          atomicAdd(Cp + 3, acc[ii][jj + 3]);
        }
      }
    }
  }
}

// ---------------------------------------------------------------------------
// Causal depthwise conv (K=4) + bias + silu on the x-slice of zxbcdt.
// out[l,c] = silu(b[c] + sum_k w[c,k] * x[l+k-3, c])
// ---------------------------------------------------------------------------
__global__ __launch_bounds__(256) void conv_silu_k(
    const float* __restrict__ zx, const float* __restrict__ cw,
    const float* __restrict__ cb, float* __restrict__ xc)
{
  const int t = blockIdx.x * 256 + threadIdx.x;  // t < L_SEQ*DXB
  const int c = t & (DXB - 1);
  const int l = t >> 9;
  const float* col = zx + OFF_X + c;
  const float w0 = cw[c * 4 + 0], w1 = cw[c * 4 + 1];
  const float w2 = cw[c * 4 + 2], w3 = cw[c * 4 + 3];
  float acc = cb[c] + w3 * col[(size_t)l * DP];
  if (l >= 1) acc = fmaf(w2, col[(size_t)(l - 1) * DP], acc);
  if (l >= 2) acc = fmaf(w1, col[(size_t)(l - 2) * DP], acc);
  if (l >= 3) acc = fmaf(w0, col[(size_t)(l - 3) * DP], acc);
  xc[t] = siluf(acc);
}

// ---------------------------------------------------------------------------
// Scan pass 1: per (g, segment) compute per-channel (p,n) running product P
// and end state h over SEGLEN steps starting from h=0.
// thread tid = p*16 + n.
// ---------------------------------------------------------------------------
__global__ __launch_bounds__(256) void scan_phase1(
    const float* __restrict__ zx, const float* __restrict__ delta,
    const float* __restrict__ xc, const float* __restrict__ A_log,
    float* __restrict__ Pout, float* __restrict__ Hout)
{
  const int g = blockIdx.x, s = blockIdx.y;
  const int tid = threadIdx.x;
  const int p = tid >> 4, n = tid & 15;
  const float Apn = -__expf(A_log[(g * 16 + p) * 16 + n]);

  __shared__ __align__(16) float sd[CHUNK][16], sx[CHUNK][16], sb[CHUNK][16];
  float h = 0.f, P = 1.f;
  const int r = tid >> 2, q = (tid & 3) << 2;
  const int gx16 = (g >> 2) * 16;

  for (int ch = 0; ch < SEGLEN / CHUNK; ++ch) {
    const int lb = s * SEGLEN + ch * CHUNK;
    __syncthreads();
    const int l = lb + r;
    *(float4*)&sd[r][q] = *(const float4*)&delta[(size_t)l * DI + g * 16 + q];
    *(float4*)&sx[r][q] = *(const float4*)&xc[(size_t)l * DXB + gx16 + q];
    *(float4*)&sb[r][q] = *(const float4*)&zx[(size_t)l * DP + OFF_B + gx16 + q];
    __syncthreads();
#pragma unroll 8
    for (int i = 0; i < CHUNK; ++i) {
      const float dt = sd[i][p];
      const float a = __expf(dt * Apn);
      h = fmaf(a, h, dt * sx[i][p] * sb[i][n]);
      P *= a;
    }
  }
  const int idx = (s * GH + g) * 256 + tid;
  Pout[idx] = P;
  Hout[idx] = h;
}

// ---------------------------------------------------------------------------
// Scan pass 2: recompute carry from segments < s, rerun scan producing
// y[l,d] = (sum_n h*C + D*x) * silu(z), written to ybuf (L x DI).
// ---------------------------------------------------------------------------
__global__ __launch_bounds__(256) void scan_phase2(
    const float* __restrict__ zx, const float* __restrict__ delta,
    const float* __restrict__ xc, const float* __restrict__ A_log,
    const float* __restrict__ Dv, const float* __restrict__ Pin,
    const float* __restrict__ Hin, float* __restrict__ ybuf)
{
  const int g = blockIdx.x, s = blockIdx.y;
  const int tid = threadIdx.x;
  const int p = tid >> 4, n = tid & 15;
  const float Apn = -__expf(A_log[(g * 16 + p) * 16 + n]);

  // carry in: combine per-segment (P, h_end) of all earlier segments
  float h = 0.f;
  for (int s2 = 0; s2 < s; ++s2) {
    const int idx = (s2 * GH + g) * 256 + tid;
    h = fmaf(Pin[idx], h, Hin[idx]);
  }

  __shared__ __align__(16) float sd[CHUNK][16], sx[CHUNK][16], sb[CHUNK][16],
                                 sc[CHUNK][16], sz[CHUNK][16], sy[CHUNK][16];
  const int r = tid >> 2, q = (tid & 3) << 2;
  const int gx16 = (g >> 2) * 16;
  const float4 dq = *(const float4*)&Dv[g * 16 + q];

  for (int ch = 0; ch < SEGLEN / CHUNK; ++ch) {
    const int lb = s * SEGLEN + ch * CHUNK;
    const int l = lb + r;
    __syncthreads();  // previous epilogue done before restaging
    *(float4*)&sd[r][q] = *(const float4*)&delta[(size_t)l * DI + g * 16 + q];
    *(float4*)&sx[r][q] = *(const float4*)&xc[(size_t)l * DXB + gx16 + q];
    *(float4*)&sb[r][q] = *(const float4*)&zx[(size_t)l * DP + OFF_B + gx16 + q];
    *(float4*)&sc[r][q] = *(const float4*)&zx[(size_t)l * DP + OFF_C + g * 16 + q];
    *(float4*)&sz[r][q] = *(const float4*)&zx[(size_t)l * DP + OFF_Z + g * 16 + q];
    __syncthreads();

    for (int i = 0; i < CHUNK; ++i) {
      const float dt = sd[i][p];
      const float a = __expf(dt * Apn);
      h = fmaf(a, h, dt * sx[i][p] * sb[i][n]);
      float yv = h * sc[i][n];
      // reduce over n (low 4 lane bits; tid = p*16+n so xor stays in-segment)
      yv += __shfl_xor(yv, 1);
      yv += __shfl_xor(yv, 2);
      yv += __shfl_xor(yv, 4);
      yv += __shfl_xor(yv, 8);
      if (n == 0) sy[i][p] = yv;
    }
    __syncthreads();

    // fused epilogue + coalesced store of this chunk
    {
      float4 y4 = *(const float4*)&sy[r][q];
      float4 x4 = *(const float4*)&sx[r][q];
      float4 z4 = *(const float4*)&sz[r][q];
      float4 o;
      o.x = (y4.x + dq.x * x4.x) * siluf(z4.x);
      o.y = (y4.y + dq.y * x4.y) * siluf(z4.y);
      o.z = (y4.z + dq.z * x4.z) * siluf(z4.z);
      o.w = (y4.w + dq.w * x4.w) * siluf(z4.w);
      *(float4*)&ybuf[(size_t)l * DI + g * 16 + q] = o;
    }
  }
}

__global__ __launch_bounds__(256) void zero_f32(float* __restrict__ p, int n4)
{
  const int t = blockIdx.x * 256 + threadIdx.x;
  if (t < n4) ((float4*)p)[t] = make_float4(0.f, 0.f, 0.f, 0.f);
}

// ---------------------------------------------------------------------------
extern "C" void kernel_launch(void* const* d_in, const int* in_sizes, int n_in,
                              void* d_out, int out_size, void* d_ws, size_t ws_size,
                              hipStream_t stream)
{
  const float* hidden  = (const float*)d_in[0];  // (L, DM)
  const float* W_in    = (const float*)d_in[1];  // (DM, DP)
  const float* conv_w  = (const float*)d_in[2];  // (DXB, 1, 4)
  const float* conv_b  = (const float*)d_in[3];  // (DXB,)
  const float* W_dt    = (const float*)d_in[4];  // (DTR, DI)
  const float* dt_bias = (const float*)d_in[5];  // (DI,)
  const float* A_log   = (const float*)d_in[6];  // (DI, DS)
  const float* Dvec    = (const float*)d_in[7];  // (DI,)
  const float* W_out   = (const float*)d_in[8];  // (DI, DM)
  float* out = (float*)d_out;                    // (L, DM)

  float* ws    = (float*)d_ws;
  float* zx    = ws;                                   // L*DP   = 10,616,832
  float* delta = zx + (size_t)L_SEQ * DP;              // L*DI   =  4,194,304
  float* xcv   = delta + (size_t)L_SEQ * DI;           // L*DXB  =  1,048,576
  float* ybuf  = xcv + (size_t)L_SEQ * DXB;            // L*DI   =  4,194,304
  float* Pbuf  = ybuf + (size_t)L_SEQ * DI;            // 262,144
  float* Hbuf  = Pbuf + (size_t)NSEG * GH * 256;       // 262,144
  // total ~82.3 MB of d_ws

  // 1. in-projection: zx = hidden @ W_in   (2048x5184, K=1024)
  gemm128<0><<<dim3(41, 16), 256, 0, stream>>>(
      hidden, DM, 0, W_in, DP, zx, DP, nullptr, L_SEQ, DP, 0, DM);

  // 2. causal depthwise conv + silu on x slice
  conv_silu_k<<<dim3((L_SEQ * DXB) / 256), 256, 0, stream>>>(zx, conv_w, conv_b, xcv);

  // 3. delta = softplus(dtr @ W_dt + 2*dt_bias)   (2048x2048, K=64)
  gemm128<1><<<dim3(16, 16), 256, 0, stream>>>(
      zx, DP, OFF_DT, W_dt, DI, delta, DI, dt_bias, L_SEQ, DI, 0, DTR);

  // 4. scan pass 1: per-segment (P, h_end)
  scan_phase1<<<dim3(GH, NSEG), 256, 0, stream>>>(zx, delta, xcv, A_log, Pbuf, Hbuf);

  // 5. scan pass 2: carry + y with fused (D*x + gate) epilogue
  scan_phase2<<<dim3(GH, NSEG), 256, 0, stream>>>(zx, delta, xcv, A_log, Dvec,
                                                  Pbuf, Hbuf, ybuf);

  // 6. out-projection: out = ybuf @ W_out (2048x1024, K=2048), split-K=4 atomic
  zero_f32<<<dim3(out_size / 4 / 256), 256, 0, stream>>>(out, out_size / 4);
  gemm128<2><<<dim3(8, 16, 4), 256, 0, stream>>>(
      ybuf, DI, 0, W_out, DM, out, DM, nullptr, L_SEQ, DM, 0, DI / 4);
}

// Round 2
// 327.667 us; speedup vs baseline: 2.1047x; 2.1047x over previous
//
#include <hip/hip_runtime.h>
#include <hip/hip_bf16.h>
#include <cstdint>

// ---- problem dims ----
#define L_SEQ   2048
#define DM      1024   // d_model
#define DI      2048   // d_inner
#define DXB     512
#define DS      16     // d_state
#define DTR     64     // dt_rank
#define GH      128    // C-heads = DI/DS
#define DP      5184   // 2*DI + 2*DXB + DTR

// zxbcdt column offsets
#define OFF_Z   0
#define OFF_X   2048
#define OFF_B   2560
#define OFF_C   3072
#define OFF_DT  5120

// scan segmentation
#define NSEG    8
#define SEGLEN  256
#define CHUNK   64

typedef __bf16 bf16x8 __attribute__((ext_vector_type(8)));
typedef float  f32x4  __attribute__((ext_vector_type(4)));

__device__ __forceinline__ float siluf(float x) {
  return x / (1.f + __expf(-x));
}
__device__ __forceinline__ float softplusf(float x) {
  return x > 20.f ? x : log1pf(__expf(x));
}
// round-to-nearest-even fp32 -> bf16
__device__ __forceinline__ unsigned short f2bf(float f) {
  union { float f; unsigned u; } v; v.f = f;
  unsigned r = v.u + 0x7fffu + ((v.u >> 16) & 1u);
  return (unsigned short)(r >> 16);
}
// async global->LDS, 16 bytes per lane. LDS dest must be wave-uniform-base + lane*16.
__device__ __forceinline__ void gload16(const unsigned short* g, unsigned short* l) {
  __builtin_amdgcn_global_load_lds((const __attribute__((address_space(1))) void*)g,
                                   (__attribute__((address_space(3))) void*)l, 16, 0, 0);
}

// ---------------------------------------------------------------------------
// bf16 MFMA GEMM: C[M,N](fp32) (+)= A[M,K](bf16,row-major) * BT[N,K](bf16)^T
// 128x128 block tile, BK=32, 4 waves each computing 64x64 (4x4 MFMA 16x16x32).
// LDS is fragment-major: slot s (16B) = tile rt=s>>6, q=(s>>4)&3, m=s&15 holds
// row (rt*16+m), k-range q*8..q*8+7 — so frag reads are ds_read_b128 at
// base+lane*16 (conflict-free) and staging is global_load_lds width 16.
// MODE 0: plain store. MODE 1: atomicAdd (split-K over blockIdx.z).
// Requires M%128==0, K%32==0; N arbitrary (clamped loads, guarded stores).
// ---------------------------------------------------------------------------
template<int MODE>
__global__ __launch_bounds__(256) void mfma_gemm(
    const unsigned short* __restrict__ A,
    const unsigned short* __restrict__ BT,
    float* __restrict__ C, int ldc,
    int N, int K, int ktiles)
{
  __shared__ __align__(16) unsigned short Asg[4096];  // 128x32 bf16, frag-major
  __shared__ __align__(16) unsigned short Bsg[4096];

  const int tid  = threadIdx.x;
  const int wave = tid >> 6, lane = tid & 63;
  const int row0 = blockIdx.y * 128;
  const int col0 = blockIdx.x * 128;
  const int kbase = blockIdx.z * ktiles * 32;

  // staging slots tid and tid+256
  const int s0 = tid, s1 = tid + 256;
  const int rt0 = s0 >> 6, q0 = (s0 >> 4) & 3, m0 = s0 & 15;
  const int rt1 = s1 >> 6, q1 = (s1 >> 4) & 3, m1 = s1 & 15;
  const size_t aoff0 = (size_t)(row0 + rt0 * 16 + m0) * K + q0 * 8 + kbase;
  const size_t aoff1 = (size_t)(row0 + rt1 * 16 + m1) * K + q1 * 8 + kbase;
  int c0i = col0 + rt0 * 16 + m0; if (c0i > N - 1) c0i = N - 1;
  int c1i = col0 + rt1 * 16 + m1; if (c1i > N - 1) c1i = N - 1;
  const size_t boff0 = (size_t)c0i * K + q0 * 8 + kbase;
  const size_t boff1 = (size_t)c1i * K + q1 * 8 + kbase;

  f32x4 acc[4][4];
#pragma unroll
  for (int i = 0; i < 4; ++i)
#pragma unroll
    for (int j = 0; j < 4; ++j) acc[i][j] = (f32x4)0.f;

  const int warow = (wave >> 1) * 4;  // row-tile base (16-row units)
  const int wacol = (wave & 1) * 4;

  for (int kt = 0; kt < ktiles; ++kt) {
    const int k0 = kt * 32;
    gload16(A  + aoff0 + k0, Asg + s0 * 8);
    gload16(A  + aoff1 + k0, Asg + s0 * 8 + 2048);
    gload16(BT + boff0 + k0, Bsg + s0 * 8);
    gload16(BT + boff1 + k0, Bsg + s0 * 8 + 2048);
    __syncthreads();  // drains vmcnt -> LDS tiles complete

    bf16x8 af[4], bfr[4];
#pragma unroll
    for (int i = 0; i < 4; ++i)
      af[i] = *(const bf16x8*)(Asg + (warow + i) * 512 + lane * 8);
#pragma unroll
    for (int j = 0; j < 4; ++j)
      bfr[j] = *(const bf16x8*)(Bsg + (wacol + j) * 512 + lane * 8);
#pragma unroll
    for (int i = 0; i < 4; ++i)
#pragma unroll
      for (int j = 0; j < 4; ++j)
        acc[i][j] = __builtin_amdgcn_mfma_f32_16x16x32_bf16(af[i], bfr[j], acc[i][j], 0, 0, 0);
    __syncthreads();  // all frag reads done before next-tile overwrite
  }

  // epilogue: C/D layout col=lane&15, row=(lane>>4)*4+reg
#pragma unroll
  for (int i = 0; i < 4; ++i) {
    const int rbase = row0 + (warow + i) * 16 + ((lane >> 4) << 2);
#pragma unroll
    for (int j = 0; j < 4; ++j) {
      const int col = col0 + (wacol + j) * 16 + (lane & 15);
      if (col < N) {
#pragma unroll
        for (int r = 0; r < 4; ++r) {
          float* p = C + (size_t)(rbase + r) * ldc + col;
          if (MODE == 0) *p = acc[i][j][r];
          else atomicAdd(p, acc[i][j][r]);
        }
      }
    }
  }
}

// ---------------------------------------------------------------------------
// fp32 GEMM (kept for the small K=64 delta GEMM). MODE 1: softplus(acc+2*bias).
// ---------------------------------------------------------------------------
template<int MODE>
__global__ __launch_bounds__(256, 2) void gemm128(
    const float* __restrict__ A, int lda, int aoff,
    const float* __restrict__ B, int ldb,
    float* __restrict__ C, int ldc,
    const float* __restrict__ bias,
    int M, int N, int Kbeg, int Klen)
{
  __shared__ __align__(16) float As[16][132];
  __shared__ __align__(16) float Bs[16][132];

  const int tid = threadIdx.x;
  const int row0 = blockIdx.y * 128;
  const int col0 = blockIdx.x * 128;
  const int kb = Kbeg + blockIdx.z * Klen;

  const int tx = tid & 15, ty = tid >> 4;
  const int ar = tid >> 2, aq = (tid & 3) << 2;
  const int br = tid >> 5, bq = (tid & 31) << 2;

  float acc[8][8];
#pragma unroll
  for (int i = 0; i < 8; ++i)
#pragma unroll
    for (int j = 0; j < 8; ++j) acc[i][j] = 0.f;

  float4 ra0, ra1, rb0, rb1;
  const int ktiles = Klen >> 4;

  auto loadG = [&](int kt) {
    const int k0 = kb + (kt << 4);
    const float* Ap = A + (size_t)(row0 + ar) * lda + aoff + k0 + aq;
    ra0 = *(const float4*)Ap;
    ra1 = *(const float4*)(Ap + (size_t)64 * lda);
    const int cb_ = col0 + bq;
    if (cb_ < N) {
      const float* Bp = B + (size_t)(k0 + br) * ldb + cb_;
      rb0 = *(const float4*)Bp;
      rb1 = *(const float4*)(Bp + (size_t)8 * ldb);
    } else {
      rb0 = make_float4(0.f, 0.f, 0.f, 0.f);
      rb1 = make_float4(0.f, 0.f, 0.f, 0.f);
    }
  };

  loadG(0);
  for (int kt = 0; kt < ktiles; ++kt) {
    __syncthreads();
    As[aq + 0][ar] = ra0.x; As[aq + 1][ar] = ra0.y;
    As[aq + 2][ar] = ra0.z; As[aq + 3][ar] = ra0.w;
    As[aq + 0][ar + 64] = ra1.x; As[aq + 1][ar + 64] = ra1.y;
    As[aq + 2][ar + 64] = ra1.z; As[aq + 3][ar + 64] = ra1.w;
    *(float4*)&Bs[br][bq] = rb0;
    *(float4*)&Bs[br + 8][bq] = rb1;
    __syncthreads();
    if (kt + 1 < ktiles) loadG(kt + 1);

#pragma unroll
    for (int k = 0; k < 16; ++k) {
      float4 a0 = *(const float4*)&As[k][ty * 4];
      float4 a1 = *(const float4*)&As[k][ty * 4 + 64];
      float4 b0 = *(const float4*)&Bs[k][tx * 4];
      float4 b1 = *(const float4*)&Bs[k][tx * 4 + 64];
      float av[8] = {a0.x, a0.y, a0.z, a0.w, a1.x, a1.y, a1.z, a1.w};
      float bv[8] = {b0.x, b0.y, b0.z, b0.w, b1.x, b1.y, b1.z, b1.w};
#pragma unroll
      for (int i = 0; i < 8; ++i)
#pragma unroll
        for (int j = 0; j < 8; ++j)
          acc[i][j] = fmaf(av[i], bv[j], acc[i][j]);
    }
  }

#pragma unroll
  for (int half = 0; half < 2; ++half) {
#pragma unroll
    for (int i = 0; i < 4; ++i) {
      const int rr = row0 + half * 64 + ty * 4 + i;
      if (rr >= M) continue;
      const int ii = half * 4 + i;
#pragma unroll
      for (int jh = 0; jh < 2; ++jh) {
        const int cc = col0 + jh * 64 + tx * 4;
        if (cc >= N) continue;
        const int jj = jh * 4;
        float* Cp = C + (size_t)rr * ldc + cc;
        if (MODE == 1) {
          float4 bi = *(const float4*)&bias[cc];
          float4 v;
          v.x = softplusf(acc[ii][jj + 0] + 2.f * bi.x);
          v.y = softplusf(acc[ii][jj + 1] + 2.f * bi.y);
          v.z = softplusf(acc[ii][jj + 2] + 2.f * bi.z);
          v.w = softplusf(acc[ii][jj + 3] + 2.f * bi.w);
          *(float4*)Cp = v;
        } else {
          float4 v = make_float4(acc[ii][jj], acc[ii][jj + 1], acc[ii][jj + 2], acc[ii][jj + 3]);
          *(float4*)Cp = v;
        }
      }
    }
  }
}

// ---------------------------------------------------------------------------
__global__ __launch_bounds__(256) void cast_bf16_k(
    const float* __restrict__ in, unsigned short* __restrict__ out, int n4)
{
  const int t = blockIdx.x * 256 + threadIdx.x;
  if (t < n4) {
    float4 v = ((const float4*)in)[t];
    ushort4 o;
    o.x = f2bf(v.x); o.y = f2bf(v.y); o.z = f2bf(v.z); o.w = f2bf(v.w);
    ((ushort4*)out)[t] = o;
  }
}

// W (R x C fp32) -> WT (C x R bf16)
__global__ __launch_bounds__(256) void transpose_cast_k(
    const float* __restrict__ W, unsigned short* __restrict__ WT, int R, int C)
{
  __shared__ float t[32][33];
  const int c0 = blockIdx.x * 32, r0 = blockIdx.y * 32;
  const int x = threadIdx.x & 31, y = threadIdx.x >> 5;
#pragma unroll
  for (int i = 0; i < 4; ++i)
    t[y * 4 + i][x] = W[(size_t)(r0 + y * 4 + i) * C + c0 + x];
  __syncthreads();
#pragma unroll
  for (int i = 0; i < 4; ++i)
    WT[(size_t)(c0 + y * 4 + i) * R + r0 + x] = f2bf(t[x][y * 4 + i]);
}

// ---------------------------------------------------------------------------
__global__ __launch_bounds__(256) void conv_silu_k(
    const float* __restrict__ zx, const float* __restrict__ cw,
    const float* __restrict__ cb, float* __restrict__ xc)
{
  const int t = blockIdx.x * 256 + threadIdx.x;
  const int c = t & (DXB - 1);
  const int l = t >> 9;
  const float* col = zx + OFF_X + c;
  const float w0 = cw[c * 4 + 0], w1 = cw[c * 4 + 1];
  const float w2 = cw[c * 4 + 2], w3 = cw[c * 4 + 3];
  float acc = cb[c] + w3 * col[(size_t)l * DP];
  if (l >= 1) acc = fmaf(w2, col[(size_t)(l - 1) * DP], acc);
  if (l >= 2) acc = fmaf(w1, col[(size_t)(l - 2) * DP], acc);
  if (l >= 3) acc = fmaf(w0, col[(size_t)(l - 3) * DP], acc);
  xc[t] = siluf(acc);
}

// ---------------------------------------------------------------------------
__global__ __launch_bounds__(256) void scan_phase1(
    const float* __restrict__ zx, const float* __restrict__ delta,
    const float* __restrict__ xc, const float* __restrict__ A_log,
    float* __restrict__ Pout, float* __restrict__ Hout)
{
  const int g = blockIdx.x, s = blockIdx.y;
  const int tid = threadIdx.x;
  const int p = tid >> 4, n = tid & 15;
  const float Apn = -__expf(A_log[(g * 16 + p) * 16 + n]);

  __shared__ __align__(16) float sd[CHUNK][16], sx[CHUNK][16], sb[CHUNK][16];
  float h = 0.f, P = 1.f;
  const int r = tid >> 2, q = (tid & 3) << 2;
  const int gx16 = (g >> 2) * 16;

  for (int ch = 0; ch < SEGLEN / CHUNK; ++ch) {
    const int lb = s * SEGLEN + ch * CHUNK;
    __syncthreads();
    const int l = lb + r;
    *(float4*)&sd[r][q] = *(const float4*)&delta[(size_t)l * DI + g * 16 + q];
    *(float4*)&sx[r][q] = *(const float4*)&xc[(size_t)l * DXB + gx16 + q];
    *(float4*)&sb[r][q] = *(const float4*)&zx[(size_t)l * DP + OFF_B + gx16 + q];
    __syncthreads();
#pragma unroll 8
    for (int i = 0; i < CHUNK; ++i) {
      const float dt = sd[i][p];
      const float a = __expf(dt * Apn);
      h = fmaf(a, h, dt * sx[i][p] * sb[i][n]);
      P *= a;
    }
  }
  const int idx = (s * GH + g) * 256 + tid;
  Pout[idx] = P;
  Hout[idx] = h;
}

// scan pass 2: writes y directly as bf16 (feeds out-proj A operand)
__global__ __launch_bounds__(256) void scan_phase2(
    const float* __restrict__ zx, const float* __restrict__ delta,
    const float* __restrict__ xc, const float* __restrict__ A_log,
    const float* __restrict__ Dv, const float* __restrict__ Pin,
    const float* __restrict__ Hin, unsigned short* __restrict__ ybuf)
{
  const int g = blockIdx.x, s = blockIdx.y;
  const int tid = threadIdx.x;
  const int p = tid >> 4, n = tid & 15;
  const float Apn = -__expf(A_log[(g * 16 + p) * 16 + n]);

  float h = 0.f;
  for (int s2 = 0; s2 < s; ++s2) {
    const int idx = (s2 * GH + g) * 256 + tid;
    h = fmaf(Pin[idx], h, Hin[idx]);
  }

  __shared__ __align__(16) float sd[CHUNK][16], sx[CHUNK][16], sb[CHUNK][16],
                                 sc[CHUNK][16], sz[CHUNK][16], sy[CHUNK][16];
  const int r = tid >> 2, q = (tid & 3) << 2;
  const int gx16 = (g >> 2) * 16;
  const float4 dq = *(const float4*)&Dv[g * 16 + q];

  for (int ch = 0; ch < SEGLEN / CHUNK; ++ch) {
    const int lb = s * SEGLEN + ch * CHUNK;
    const int l = lb + r;
    __syncthreads();
    *(float4*)&sd[r][q] = *(const float4*)&delta[(size_t)l * DI + g * 16 + q];
    *(float4*)&sx[r][q] = *(const float4*)&xc[(size_t)l * DXB + gx16 + q];
    *(float4*)&sb[r][q] = *(const float4*)&zx[(size_t)l * DP + OFF_B + gx16 + q];
    *(float4*)&sc[r][q] = *(const float4*)&zx[(size_t)l * DP + OFF_C + g * 16 + q];
    *(float4*)&sz[r][q] = *(const float4*)&zx[(size_t)l * DP + OFF_Z + g * 16 + q];
    __syncthreads();

    for (int i = 0; i < CHUNK; ++i) {
      const float dt = sd[i][p];
      const float a = __expf(dt * Apn);
      h = fmaf(a, h, dt * sx[i][p] * sb[i][n]);
      float yv = h * sc[i][n];
      yv += __shfl_xor(yv, 1);
      yv += __shfl_xor(yv, 2);
      yv += __shfl_xor(yv, 4);
      yv += __shfl_xor(yv, 8);
      if (n == 0) sy[i][p] = yv;
    }
    __syncthreads();

    {
      float4 y4 = *(const float4*)&sy[r][q];
      float4 x4 = *(const float4*)&sx[r][q];
      float4 z4 = *(const float4*)&sz[r][q];
      ushort4 ob;
      ob.x = f2bf((y4.x + dq.x * x4.x) * siluf(z4.x));
      ob.y = f2bf((y4.y + dq.y * x4.y) * siluf(z4.y));
      ob.z = f2bf((y4.z + dq.z * x4.z) * siluf(z4.z));
      ob.w = f2bf((y4.w + dq.w * x4.w) * siluf(z4.w));
      *(ushort4*)&ybuf[(size_t)l * DI + g * 16 + q] = ob;
    }
  }
}

__global__ __launch_bounds__(256) void zero_f32(float* __restrict__ p, int n4)
{
  const int t = blockIdx.x * 256 + threadIdx.x;
  if (t < n4) ((float4*)p)[t] = make_float4(0.f, 0.f, 0.f, 0.f);
}

// ---------------------------------------------------------------------------
extern "C" void kernel_launch(void* const* d_in, const int* in_sizes, int n_in,
                              void* d_out, int out_size, void* d_ws, size_t ws_size,
                              hipStream_t stream)
{
  const float* hidden  = (const float*)d_in[0];
  const float* W_in    = (const float*)d_in[1];
  const float* conv_w  = (const float*)d_in[2];
  const float* conv_b  = (const float*)d_in[3];
  const float* W_dt    = (const float*)d_in[4];
  const float* dt_bias = (const float*)d_in[5];
  const float* A_log   = (const float*)d_in[6];
  const float* Dvec    = (const float*)d_in[7];
  const float* W_out   = (const float*)d_in[8];
  float* out = (float*)d_out;

  // workspace layout (total = 82,313,216 B, same as proven round-1 usage)
  float* ws    = (float*)d_ws;
  float* zx    = ws;                                   // 10,616,832 f32
  float* delta = zx + (size_t)L_SEQ * DP;              //  4,194,304 f32
  float* xcv   = delta + (size_t)L_SEQ * DI;           //  1,048,576 f32
  float* Pbuf  = xcv + (size_t)L_SEQ * DXB;            //    262,144 f32
  float* Hbuf  = Pbuf + (size_t)NSEG * GH * 256;       //    262,144 f32
  unsigned short* Abf = (unsigned short*)(Hbuf + (size_t)NSEG * GH * 256); // 2,097,152 u16
  unsigned short* U   = Abf + (size_t)L_SEQ * DM;      // union region: 6,291,456 u16
  unsigned short* WinT  = U;                           // 5,308,416 u16 (dead after step 3)
  unsigned short* Ybf   = U;                           // 4,194,304 u16
  unsigned short* WoutT = U + (size_t)L_SEQ * DI;      // 2,097,152 u16

  // 1. cast hidden -> bf16; transpose+cast W_in -> (DP x DM) bf16
  cast_bf16_k<<<dim3((L_SEQ * DM / 4) / 256), 256, 0, stream>>>(hidden, Abf, L_SEQ * DM / 4);
  transpose_cast_k<<<dim3(DP / 32, DM / 32), 256, 0, stream>>>(W_in, WinT, DM, DP);

  // 2. in-projection (bf16 MFMA): zx = hidden @ W_in  (2048 x 5184, K=1024)
  mfma_gemm<0><<<dim3(41, 16), 256, 0, stream>>>(Abf, WinT, zx, DP, DP, DM, DM / 32);

  // 3. causal depthwise conv + silu
  conv_silu_k<<<dim3((L_SEQ * DXB) / 256), 256, 0, stream>>>(zx, conv_w, conv_b, xcv);

  // 4. delta = softplus(dtr @ W_dt + 2*dt_bias)  (fp32, K=64)
  gemm128<1><<<dim3(16, 16), 256, 0, stream>>>(
      zx, DP, OFF_DT, W_dt, DI, delta, DI, dt_bias, L_SEQ, DI, 0, DTR);

  // 5. scan pass 1
  scan_phase1<<<dim3(GH, NSEG), 256, 0, stream>>>(zx, delta, xcv, A_log, Pbuf, Hbuf);

  // 6. transpose+cast W_out -> (DM x DI) bf16 (after step 2: aliases WinT tail)
  transpose_cast_k<<<dim3(DM / 32, DI / 32), 256, 0, stream>>>(W_out, WoutT, DI, DM);

  // 7. scan pass 2 -> y as bf16 (aliases WinT head; after step 2)
  scan_phase2<<<dim3(GH, NSEG), 256, 0, stream>>>(zx, delta, xcv, A_log, Dvec,
                                                  Pbuf, Hbuf, Ybf);

  // 8. out-projection (bf16 MFMA, split-K=4 atomic): out = y @ W_out
  zero_f32<<<dim3(out_size / 4 / 256), 256, 0, stream>>>(out, out_size / 4);
  mfma_gemm<1><<<dim3(8, 16, 4), 256, 0, stream>>>(Ybf, WoutT, out, DM, DM, DI, DI / 4 / 32);
}

// Round 3
// 285.956 us; speedup vs baseline: 2.4117x; 1.1459x over previous
//
#include <hip/hip_runtime.h>
#include <hip/hip_bf16.h>
#include <cstdint>

// ---- problem dims ----
#define L_SEQ   2048
#define DM      1024   // d_model
#define DI      2048   // d_inner
#define DXB     512
#define DS      16     // d_state
#define DTR     64     // dt_rank
#define GH      128    // C-heads = DI/DS
#define DP      5184   // 2*DI + 2*DXB + DTR

// zxbcdt column offsets
#define OFF_Z   0
#define OFF_X   2048
#define OFF_B   2560
#define OFF_C   3072
#define OFF_DT  5120

// scan segmentation: 64 segments x 32 steps -> 512 blocks/scan kernel
#define NSEG    64
#define SEGLEN  32

typedef __bf16 bf16x8 __attribute__((ext_vector_type(8)));
typedef float  f32x4  __attribute__((ext_vector_type(4)));

__device__ __forceinline__ float siluf(float x) {
  return x / (1.f + __expf(-x));
}
__device__ __forceinline__ float softplusf(float x) {
  return x > 20.f ? x : log1pf(__expf(x));
}
__device__ __forceinline__ unsigned short f2bf(float f) {
  union { float f; unsigned u; } v; v.f = f;
  unsigned r = v.u + 0x7fffu + ((v.u >> 16) & 1u);
  return (unsigned short)(r >> 16);
}
// async global->LDS, 16B/lane. LDS dest must be wave-uniform base + lane*16.
__device__ __forceinline__ void gload16(const void* g, void* l) {
  __builtin_amdgcn_global_load_lds((const __attribute__((address_space(1))) void*)g,
                                   (__attribute__((address_space(3))) void*)l, 16, 0, 0);
}

// ---------------------------------------------------------------------------
// bf16 MFMA GEMM (unchanged from R2): C[M,N](f32) (+)= A[M,K]bf16 * BT[N,K]^T
// ---------------------------------------------------------------------------
template<int MODE>
__global__ __launch_bounds__(256) void mfma_gemm(
    const unsigned short* __restrict__ A,
    const unsigned short* __restrict__ BT,
    float* __restrict__ C, int ldc,
    int N, int K, int ktiles)
{
  __shared__ __align__(16) unsigned short Asg[4096];
  __shared__ __align__(16) unsigned short Bsg[4096];

  const int tid  = threadIdx.x;
  const int wave = tid >> 6, lane = tid & 63;
  const int row0 = blockIdx.y * 128;
  const int col0 = blockIdx.x * 128;
  const int kbase = blockIdx.z * ktiles * 32;

  const int s0 = tid, s1 = tid + 256;
  const int rt0 = s0 >> 6, q0 = (s0 >> 4) & 3, m0 = s0 & 15;
  const int rt1 = s1 >> 6, q1 = (s1 >> 4) & 3, m1 = s1 & 15;
  const size_t aoff0 = (size_t)(row0 + rt0 * 16 + m0) * K + q0 * 8 + kbase;
  const size_t aoff1 = (size_t)(row0 + rt1 * 16 + m1) * K + q1 * 8 + kbase;
  int c0i = col0 + rt0 * 16 + m0; if (c0i > N - 1) c0i = N - 1;
  int c1i = col0 + rt1 * 16 + m1; if (c1i > N - 1) c1i = N - 1;
  const size_t boff0 = (size_t)c0i * K + q0 * 8 + kbase;
  const size_t boff1 = (size_t)c1i * K + q1 * 8 + kbase;

  f32x4 acc[4][4];
#pragma unroll
  for (int i = 0; i < 4; ++i)
#pragma unroll
    for (int j = 0; j < 4; ++j) acc[i][j] = (f32x4)0.f;

  const int warow = (wave >> 1) * 4;
  const int wacol = (wave & 1) * 4;

  for (int kt = 0; kt < ktiles; ++kt) {
    const int k0 = kt * 32;
    gload16(A  + aoff0 + k0, Asg + s0 * 8);
    gload16(A  + aoff1 + k0, Asg + s0 * 8 + 2048);
    gload16(BT + boff0 + k0, Bsg + s0 * 8);
    gload16(BT + boff1 + k0, Bsg + s0 * 8 + 2048);
    __syncthreads();

    bf16x8 af[4], bfr[4];
#pragma unroll
    for (int i = 0; i < 4; ++i)
      af[i] = *(const bf16x8*)(Asg + (warow + i) * 512 + lane * 8);
#pragma unroll
    for (int j = 0; j < 4; ++j)
      bfr[j] = *(const bf16x8*)(Bsg + (wacol + j) * 512 + lane * 8);
#pragma unroll
    for (int i = 0; i < 4; ++i)
#pragma unroll
      for (int j = 0; j < 4; ++j)
        acc[i][j] = __builtin_amdgcn_mfma_f32_16x16x32_bf16(af[i], bfr[j], acc[i][j], 0, 0, 0);
    __syncthreads();
  }

#pragma unroll
  for (int i = 0; i < 4; ++i) {
    const int rbase = row0 + (warow + i) * 16 + ((lane >> 4) << 2);
#pragma unroll
    for (int j = 0; j < 4; ++j) {
      const int col = col0 + (wacol + j) * 16 + (lane & 15);
      if (col < N) {
#pragma unroll
        for (int r = 0; r < 4; ++r) {
          float* p = C + (size_t)(rbase + r) * ldc + col;
          if (MODE == 0) *p = acc[i][j][r];
          else atomicAdd(p, acc[i][j][r]);
        }
      }
    }
  }
}

// ---------------------------------------------------------------------------
// fp32 GEMM for the K=64 delta GEMM. MODE 1: softplus(acc + 2*bias[col]).
// ---------------------------------------------------------------------------
template<int MODE>
__global__ __launch_bounds__(256, 2) void gemm128(
    const float* __restrict__ A, int lda, int aoff,
    const float* __restrict__ B, int ldb,
    float* __restrict__ C, int ldc,
    const float* __restrict__ bias,
    int M, int N, int Kbeg, int Klen)
{
  __shared__ __align__(16) float As[16][132];
  __shared__ __align__(16) float Bs[16][132];

  const int tid = threadIdx.x;
  const int row0 = blockIdx.y * 128;
  const int col0 = blockIdx.x * 128;
  const int kb = Kbeg + blockIdx.z * Klen;

  const int tx = tid & 15, ty = tid >> 4;
  const int ar = tid >> 2, aq = (tid & 3) << 2;
  const int br = tid >> 5, bq = (tid & 31) << 2;

  float acc[8][8];
#pragma unroll
  for (int i = 0; i < 8; ++i)
#pragma unroll
    for (int j = 0; j < 8; ++j) acc[i][j] = 0.f;

  float4 ra0, ra1, rb0, rb1;
  const int ktiles = Klen >> 4;

  auto loadG = [&](int kt) {
    const int k0 = kb + (kt << 4);
    const float* Ap = A + (size_t)(row0 + ar) * lda + aoff + k0 + aq;
    ra0 = *(const float4*)Ap;
    ra1 = *(const float4*)(Ap + (size_t)64 * lda);
    const int cb_ = col0 + bq;
    if (cb_ < N) {
      const float* Bp = B + (size_t)(k0 + br) * ldb + cb_;
      rb0 = *(const float4*)Bp;
      rb1 = *(const float4*)(Bp + (size_t)8 * ldb);
    } else {
      rb0 = make_float4(0.f, 0.f, 0.f, 0.f);
      rb1 = make_float4(0.f, 0.f, 0.f, 0.f);
    }
  };

  loadG(0);
  for (int kt = 0; kt < ktiles; ++kt) {
    __syncthreads();
    As[aq + 0][ar] = ra0.x; As[aq + 1][ar] = ra0.y;
    As[aq + 2][ar] = ra0.z; As[aq + 3][ar] = ra0.w;
    As[aq + 0][ar + 64] = ra1.x; As[aq + 1][ar + 64] = ra1.y;
    As[aq + 2][ar + 64] = ra1.z; As[aq + 3][ar + 64] = ra1.w;
    *(float4*)&Bs[br][bq] = rb0;
    *(float4*)&Bs[br + 8][bq] = rb1;
    __syncthreads();
    if (kt + 1 < ktiles) loadG(kt + 1);

#pragma unroll
    for (int k = 0; k < 16; ++k) {
      float4 a0 = *(const float4*)&As[k][ty * 4];
      float4 a1 = *(const float4*)&As[k][ty * 4 + 64];
      float4 b0 = *(const float4*)&Bs[k][tx * 4];
      float4 b1 = *(const float4*)&Bs[k][tx * 4 + 64];
      float av[8] = {a0.x, a0.y, a0.z, a0.w, a1.x, a1.y, a1.z, a1.w};
      float bv[8] = {b0.x, b0.y, b0.z, b0.w, b1.x, b1.y, b1.z, b1.w};
#pragma unroll
      for (int i = 0; i < 8; ++i)
#pragma unroll
        for (int j = 0; j < 8; ++j)
          acc[i][j] = fmaf(av[i], bv[j], acc[i][j]);
    }
  }

#pragma unroll
  for (int half = 0; half < 2; ++half) {
#pragma unroll
    for (int i = 0; i < 4; ++i) {
      const int rr = row0 + half * 64 + ty * 4 + i;
      if (rr >= M) continue;
      const int ii = half * 4 + i;
#pragma unroll
      for (int jh = 0; jh < 2; ++jh) {
        const int cc = col0 + jh * 64 + tx * 4;
        if (cc >= N) continue;
        const int jj = jh * 4;
        float* Cp = C + (size_t)rr * ldc + cc;
        if (MODE == 1) {
          float4 bi = *(const float4*)&bias[cc];
          float4 v;
          v.x = softplusf(acc[ii][jj + 0] + 2.f * bi.x);
          v.y = softplusf(acc[ii][jj + 1] + 2.f * bi.y);
          v.z = softplusf(acc[ii][jj + 2] + 2.f * bi.z);
          v.w = softplusf(acc[ii][jj + 3] + 2.f * bi.w);
          *(float4*)Cp = v;
        } else {
          float4 v = make_float4(acc[ii][jj], acc[ii][jj + 1], acc[ii][jj + 2], acc[ii][jj + 3]);
          *(float4*)Cp = v;
        }
      }
    }
  }
}

// ---------------------------------------------------------------------------
__global__ __launch_bounds__(256) void cast_bf16_k(
    const float* __restrict__ in, unsigned short* __restrict__ out, int n4)
{
  const int t = blockIdx.x * 256 + threadIdx.x;
  if (t < n4) {
    float4 v = ((const float4*)in)[t];
    ushort4 o;
    o.x = f2bf(v.x); o.y = f2bf(v.y); o.z = f2bf(v.z); o.w = f2bf(v.w);
    ((ushort4*)out)[t] = o;
  }
}

// W (R x C fp32) -> WT (C x R bf16)
__global__ __launch_bounds__(256) void transpose_cast_k(
    const float* __restrict__ W, unsigned short* __restrict__ WT, int R, int C)
{
  __shared__ float t[32][33];
  const int c0 = blockIdx.x * 32, r0 = blockIdx.y * 32;
  const int x = threadIdx.x & 31, y = threadIdx.x >> 5;
#pragma unroll
  for (int i = 0; i < 4; ++i)
    t[y * 4 + i][x] = W[(size_t)(r0 + y * 4 + i) * C + c0 + x];
  __syncthreads();
#pragma unroll
  for (int i = 0; i < 4; ++i)
    WT[(size_t)(c0 + y * 4 + i) * R + r0 + x] = f2bf(t[x][y * 4 + i]);
}

// ---------------------------------------------------------------------------
__global__ __launch_bounds__(256) void conv_silu_k(
    const float* __restrict__ zx, const float* __restrict__ cw,
    const float* __restrict__ cb, float* __restrict__ xc)
{
  const int t = blockIdx.x * 256 + threadIdx.x;
  const int c = t & (DXB - 1);
  const int l = t >> 9;
  const float* col = zx + OFF_X + c;
  const float w0 = cw[c * 4 + 0], w1 = cw[c * 4 + 1];
  const float w2 = cw[c * 4 + 2], w3 = cw[c * 4 + 3];
  float acc = cb[c] + w3 * col[(size_t)l * DP];
  if (l >= 1) acc = fmaf(w2, col[(size_t)(l - 1) * DP], acc);
  if (l >= 2) acc = fmaf(w1, col[(size_t)(l - 2) * DP], acc);
  if (l >= 3) acc = fmaf(w0, col[(size_t)(l - 3) * DP], acc);
  xc[t] = siluf(acc);
}

// ---------------------------------------------------------------------------
// Scan pass 1 (registers-per-(g,p) version). Block = (gb, s): 16 local g x 16 p.
// Thread owns 16 n-states in registers; no cross-lane ops, one barrier total.
// Outputs per segment: S (sum of dt) and segment-end state H (from h=0).
// ---------------------------------------------------------------------------
__global__ __launch_bounds__(256) void scan_p1(
    const float* __restrict__ zx, const float* __restrict__ delta,
    const float* __restrict__ xcv, const float* __restrict__ A_log,
    float* __restrict__ Sout, float* __restrict__ Hout)
{
  const int gb = blockIdx.x, s = blockIdx.y;
  const int tid = threadIdx.x;
  const int lg = tid >> 4, p = tid & 15;
  const int l0 = s * SEGLEN;

  __shared__ __align__(16) float sB[SEGLEN][64];
  __shared__ __align__(16) float sx[SEGLEN][64];

  // stage B, x for the whole segment (global_load_lds width 16)
#pragma unroll
  for (int rep = 0; rep < 2; ++rep) {
    const int idx = rep * 256 + tid;           // float4 slot
    const int i = idx >> 4, j4 = (idx & 15) << 2;
    gload16(&zx[(size_t)(l0 + i) * DP + OFF_B + gb * 64 + j4], &sB[0][0] + idx * 4);
    gload16(&xcv[(size_t)(l0 + i) * DXB + gb * 64 + j4], &sx[0][0] + idx * 4);
  }

  float An[16];
  {
    const float* ap = A_log + (size_t)gb * 4096 + tid * 16;  // flat (g,p,n)
#pragma unroll
    for (int n = 0; n < 16; ++n) An[n] = -__expf(ap[n]);
  }
  __syncthreads();

  float h[16];
#pragma unroll
  for (int n = 0; n < 16; ++n) h[n] = 0.f;
  float S = 0.f;

  const float* dtp = delta + (size_t)l0 * DI + gb * 256 + tid;
  const int xj = ((lg >> 2) << 4) + p;
  const int bj = (lg >> 2) << 4;

  float dtc = dtp[0];
  for (int i = 0; i < SEGLEN; ++i) {
    const float dt = dtc;
    if (i + 1 < SEGLEN) dtc = dtp[(size_t)(i + 1) * DI];
    const float dtx = dt * sx[i][xj];
    S += dt;
#pragma unroll
    for (int nq = 0; nq < 4; ++nq) {
      const float4 b4 = *(const float4*)&sB[i][bj + nq * 4];
      const float bb[4] = {b4.x, b4.y, b4.z, b4.w};
#pragma unroll
      for (int k = 0; k < 4; ++k) {
        const int n = nq * 4 + k;
        const float a = __expf(dt * An[n]);
        h[n] = fmaf(a, h[n], dtx * bb[k]);
      }
    }
  }

  Sout[(size_t)s * 2048 + gb * 256 + tid] = S;
  float* hp = Hout + (size_t)s * 32768 + (size_t)gb * 4096 + tid * 16;
#pragma unroll
  for (int nq = 0; nq < 4; ++nq)
    *(float4*)(hp + nq * 4) = make_float4(h[nq * 4], h[nq * 4 + 1], h[nq * 4 + 2], h[nq * 4 + 3]);
}

// ---------------------------------------------------------------------------
// Carry kernel: exclusive scan over segments per flat state e=(g,p,n).
// P_seg = exp(A * S_seg). Hcarry[s] = state entering segment s.
// ---------------------------------------------------------------------------
__global__ __launch_bounds__(256) void scan_carry(
    const float* __restrict__ A_log, const float* __restrict__ Sin,
    const float* __restrict__ Hin, float* __restrict__ Hcarry)
{
  const int e = blockIdx.x * 256 + threadIdx.x;  // 32768 states
  const float An = -__expf(A_log[e]);
  const int gp = e >> 4;
  float h = 0.f;
  for (int s = 0; s < NSEG; ++s) {
    Hcarry[(size_t)s * 32768 + e] = h;
    const float P = __expf(An * Sin[(size_t)s * 2048 + gp]);
    h = fmaf(P, h, Hin[(size_t)s * 32768 + e]);
  }
}

// ---------------------------------------------------------------------------
// Scan pass 2: load carry, rerun segment, fused y/D/gate epilogue -> bf16 y.
// ---------------------------------------------------------------------------
__global__ __launch_bounds__(256) void scan_p2(
    const float* __restrict__ zx, const float* __restrict__ delta,
    const float* __restrict__ xcv, const float* __restrict__ A_log,
    const float* __restrict__ Dv, const float* __restrict__ Hcarry,
    unsigned short* __restrict__ ybuf)
{
  const int gb = blockIdx.x, s = blockIdx.y;
  const int tid = threadIdx.x;
  const int lg = tid >> 4, p = tid & 15;
  const int l0 = s * SEGLEN;

  __shared__ __align__(16) float sC[SEGLEN][256];
  __shared__ __align__(16) float sB[SEGLEN][64];
  __shared__ __align__(16) float sx[SEGLEN][64];

#pragma unroll
  for (int rep = 0; rep < 8; ++rep) {
    const int idx = rep * 256 + tid;           // float4 slot in sC
    const int i = idx >> 6, j4 = (idx & 63) << 2;
    gload16(&zx[(size_t)(l0 + i) * DP + OFF_C + gb * 256 + j4], &sC[0][0] + idx * 4);
  }
#pragma unroll
  for (int rep = 0; rep < 2; ++rep) {
    const int idx = rep * 256 + tid;
    const int i = idx >> 4, j4 = (idx & 15) << 2;
    gload16(&zx[(size_t)(l0 + i) * DP + OFF_B + gb * 64 + j4], &sB[0][0] + idx * 4);
    gload16(&xcv[(size_t)(l0 + i) * DXB + gb * 64 + j4], &sx[0][0] + idx * 4);
  }

  float An[16], h[16];
  {
    const float* ap = A_log + (size_t)gb * 4096 + tid * 16;
#pragma unroll
    for (int n = 0; n < 16; ++n) An[n] = -__expf(ap[n]);
    const float* hp = Hcarry + (size_t)s * 32768 + (size_t)gb * 4096 + tid * 16;
#pragma unroll
    for (int nq = 0; nq < 4; ++nq) {
      const float4 h4 = *(const float4*)(hp + nq * 4);
      h[nq * 4] = h4.x; h[nq * 4 + 1] = h4.y; h[nq * 4 + 2] = h4.z; h[nq * 4 + 3] = h4.w;
    }
  }
  const float Dd = Dv[gb * 256 + tid];
  __syncthreads();

  const float* dtp = delta + (size_t)l0 * DI + gb * 256 + tid;
  const float* zp  = zx + (size_t)l0 * DP + OFF_Z + gb * 256 + tid;
  unsigned short* yp = ybuf + (size_t)l0 * DI + gb * 256 + tid;
  const int xj = ((lg >> 2) << 4) + p;
  const int bj = (lg >> 2) << 4;
  const int cj = lg << 4;

  float dtc = dtp[0], zc = zp[0];
  for (int i = 0; i < SEGLEN; ++i) {
    const float dt = dtc, zv = zc;
    if (i + 1 < SEGLEN) {
      dtc = dtp[(size_t)(i + 1) * DI];
      zc  = zp[(size_t)(i + 1) * DP];
    }
    const float xv = sx[i][xj];
    const float dtx = dt * xv;
    float y = 0.f;
#pragma unroll
    for (int nq = 0; nq < 4; ++nq) {
      const float4 b4 = *(const float4*)&sB[i][bj + nq * 4];
      const float4 c4 = *(const float4*)&sC[i][cj + nq * 4];
      const float bb[4] = {b4.x, b4.y, b4.z, b4.w};
      const float cc[4] = {c4.x, c4.y, c4.z, c4.w};
#pragma unroll
      for (int k = 0; k < 4; ++k) {
        const int n = nq * 4 + k;
        const float a = __expf(dt * An[n]);
        h[n] = fmaf(a, h[n], dtx * bb[k]);
        y = fmaf(h[n], cc[k], y);
      }
    }
    yp[(size_t)i * DI] = f2bf((y + Dd * xv) * siluf(zv));
  }
}

__global__ __launch_bounds__(256) void zero_f32(float* __restrict__ p, int n4)
{
  const int t = blockIdx.x * 256 + threadIdx.x;
  if (t < n4) ((float4*)p)[t] = make_float4(0.f, 0.f, 0.f, 0.f);
}

// ---------------------------------------------------------------------------
extern "C" void kernel_launch(void* const* d_in, const int* in_sizes, int n_in,
                              void* d_out, int out_size, void* d_ws, size_t ws_size,
                              hipStream_t stream)
{
  const float* hidden  = (const float*)d_in[0];
  const float* W_in    = (const float*)d_in[1];
  const float* conv_w  = (const float*)d_in[2];
  const float* conv_b  = (const float*)d_in[3];
  const float* W_dt    = (const float*)d_in[4];
  const float* dt_bias = (const float*)d_in[5];
  const float* A_log   = (const float*)d_in[6];
  const float* Dvec    = (const float*)d_in[7];
  const float* W_out   = (const float*)d_in[8];
  float* out = (float*)d_out;

  // --- workspace layout (lifetime-aliased; max footprint 80,740,352 B) ---
  float* ws = (float*)d_ws;
  float* zx     = ws;                       // [0, 10,616,832) f32 — alive all
  float* delta  = ws + 10616832;            // [10,616,832, 14,811,136) f32
  float* xcv    = ws + 14811136;            // [14,811,136, 15,859,712) f32
  float* Sbuf   = ws + 15859712;            // 131,072 f32
  float* Hbuf   = ws + 15990784;            // 2,097,152 f32 (ends 18,087,936)
  float* Hcarry = ws + 18087936;            // 2,097,152 f32 (ends 20,185,088)
  // phase-A aliases (dead before delta/xcv written):
  unsigned short* Abf  = (unsigned short*)(ws + 10616832);  // 2,097,152 u16
  unsigned short* WinT = (unsigned short*)(ws + 11665408);  // 5,308,416 u16 (ends f32 14,319,616)
  // phase-D/E aliases:
  unsigned short* Ybf   = (unsigned short*)(ws + 15859712); // 4,194,304 u16 over S+H (dead after carry)
  unsigned short* WoutT = (unsigned short*)(ws + 10616832); // 2,097,152 u16 over delta (dead after scan_p2)

  // 1. cast hidden -> bf16; transpose+cast W_in
  cast_bf16_k<<<dim3((L_SEQ * DM / 4) / 256), 256, 0, stream>>>(hidden, Abf, L_SEQ * DM / 4);
  transpose_cast_k<<<dim3(DP / 32, DM / 32), 256, 0, stream>>>(W_in, WinT, DM, DP);

  // 2. in-projection (bf16 MFMA): zx = hidden @ W_in  (2048 x 5184, K=1024)
  mfma_gemm<0><<<dim3(41, 16), 256, 0, stream>>>(Abf, WinT, zx, DP, DP, DM, DM / 32);

  // 3. causal depthwise conv + silu
  conv_silu_k<<<dim3((L_SEQ * DXB) / 256), 256, 0, stream>>>(zx, conv_w, conv_b, xcv);

  // 4. delta = softplus(dtr @ W_dt + 2*dt_bias)  (fp32, K=64)
  gemm128<1><<<dim3(16, 16), 256, 0, stream>>>(
      zx, DP, OFF_DT, W_dt, DI, delta, DI, dt_bias, L_SEQ, DI, 0, DTR);

  // 5. scan pass 1: per-segment (S, H)
  scan_p1<<<dim3(8, NSEG), 256, 0, stream>>>(zx, delta, xcv, A_log, Sbuf, Hbuf);

  // 6. exclusive segment-carry scan
  scan_carry<<<dim3(128), 256, 0, stream>>>(A_log, Sbuf, Hbuf, Hcarry);

  // 7. scan pass 2 -> y (bf16) with fused D*x + silu(z) gate
  scan_p2<<<dim3(8, NSEG), 256, 0, stream>>>(zx, delta, xcv, A_log, Dvec, Hcarry, Ybf);

  // 8. transpose+cast W_out (into delta region, dead after scan_p2)
  transpose_cast_k<<<dim3(DM / 32, DI / 32), 256, 0, stream>>>(W_out, WoutT, DI, DM);

  // 9. out-projection (bf16 MFMA, split-K=4 atomic)
  zero_f32<<<dim3(out_size / 4 / 256), 256, 0, stream>>>(out, out_size / 4);
  mfma_gemm<1><<<dim3(8, 16, 4), 256, 0, stream>>>(Ybf, WoutT, out, DM, DM, DI, DI / 4 / 32);
}